// Round 5
// baseline (181.522 us; speedup 1.0000x reference)
//
#include <hip/hip_runtime.h>
#include <hip/hip_bf16.h>

// MultiHeadAttention: B=4, T=2048, DIM=64, H=12. fp32 I/O.
// Flat-reshape semantics: QKV are (8192,768) row-major; attention slices are
// contiguous 131072-elem chunks. Roles: queries = K rows (i), keys = Q rows
// (j), values = V rows, softmax over j.
// Round 12: RESUBMIT of the round-11 bisect (round-4 was an infra failure;
// the kernel never ran). Round-7 source verbatim (attn, prep, vtrans, out
// byte-identical to the verified 179.5us kernel) with exactly ONE change:
// qkv col-tiles split over gridDim.y=6 (3 waves/SIMD instead of 1).
// Pass -> rounds-8/9/10 failures came from the 4-wave out_kernel rewrite.
// Fail -> the qkv y-split is guilty despite on-paper proof.

#define DIM 64
#define NH 12
#define HD 768
#define BT 8192
#define TSEQ 2048
#define NSLICE 48
#define SLICE (TSEQ*DIM)

#define LDQ 72   // LDS row strides (ushorts): 16B-aligned rows, 2-way banks
#define LDP 72
#define LDT 72

typedef unsigned short ushort;
typedef __attribute__((ext_vector_type(8))) short bf16x8;
typedef __attribute__((ext_vector_type(4))) float f32x4;

#define SCALE2 0.18033688011112042f   // 0.125 * log2(e)

__device__ __forceinline__ ushort f2b(float f) {
    union { float f; unsigned int i; } v; v.f = f;
    unsigned int x = v.i;
    return (ushort)((x + 0x7fffu + ((x >> 16) & 1u)) >> 16);  // RNE
}

// ---------------- prep: transpose + convert weights ------------------------
// 48 blocks: z = bx/12 (Wq,Wk,Wv,Wo), tile = bx%12.
__global__ __launch_bounds__(256) void prep_w(
    const float* __restrict__ Wq, const float* __restrict__ Wk,
    const float* __restrict__ Wv, const float* __restrict__ Wo,
    ushort* __restrict__ Wt, ushort* __restrict__ Wot)
{
    __shared__ float tile[64][65];
    int bx = blockIdx.x;
    int z = bx / 12, bt = bx % 12;
    const float* __restrict__ IN = (z == 0) ? Wq : (z == 1) ? Wk : (z == 2) ? Wv : Wo;
    int inStride  = (z < 3) ? HD : DIM;
    int outStride = (z < 3) ? DIM : HD;
    int rbase = (z < 3) ? 0 : bt * 64;
    int cbase = (z < 3) ? bt * 64 : 0;
    ushort* __restrict__ OUT = (z < 3) ? (Wt + (size_t)z * HD * DIM) : Wot;
    int t = threadIdx.x;
    int r = t >> 2, c0 = (t & 3) * 16;
    #pragma unroll
    for (int cc = 0; cc < 16; cc += 4) {
        float4 a = *(const float4*)&IN[(size_t)(rbase + r) * inStride + cbase + c0 + cc];
        tile[r][c0 + cc] = a.x; tile[r][c0 + cc + 1] = a.y;
        tile[r][c0 + cc + 2] = a.z; tile[r][c0 + cc + 3] = a.w;
    }
    __syncthreads();
    int cl = t >> 2, r0 = (t & 3) * 16;
    ushort tmp[16] __attribute__((aligned(16)));
    #pragma unroll
    for (int rr = 0; rr < 16; ++rr) tmp[rr] = f2b(tile[r0 + rr][cl]);
    *(float4*)&OUT[(size_t)(cbase + cl) * outStride + rbase + r0] = *(const float4*)tmp;
    *(float4*)&OUT[(size_t)(cbase + cl) * outStride + rbase + r0 + 8] = *(const float4*)&tmp[8];
}

// ---------------- Kernel 1: Q/K/V = x @ W (MFMA; x read as fp32) -----------
// grid (128 row-tiles, 6 col-groups), 256 thr = 4 waves; wave owns 16 rows
// and loops 6 col-tiles (3072 waves = 3/SIMD). Q written pre-scaled by SCALE2.
__global__ __launch_bounds__(256) void qkv_kernel(
    const float* __restrict__ x, const ushort* __restrict__ Wt,
    ushort* __restrict__ Q, ushort* __restrict__ K, ushort* __restrict__ V)
{
    int rt = blockIdx.x, yg = blockIdx.y;
    int t = threadIdx.x, w = t >> 6, lane = t & 63;
    int ln = lane & 15, q = lane >> 4;
    int m0 = rt * 64 + w * 16;

    // A-frags from fp32 x, converted in-reg (once per wave)
    float4 xa = *(const float4*)&x[(size_t)(m0 + ln) * DIM + q * 8];
    float4 xb_ = *(const float4*)&x[(size_t)(m0 + ln) * DIM + q * 8 + 4];
    float4 xc = *(const float4*)&x[(size_t)(m0 + ln) * DIM + 32 + q * 8];
    float4 xd = *(const float4*)&x[(size_t)(m0 + ln) * DIM + 32 + q * 8 + 4];
    ushort ta[8] __attribute__((aligned(16)));
    ushort tb[8] __attribute__((aligned(16)));
    ta[0]=f2b(xa.x); ta[1]=f2b(xa.y); ta[2]=f2b(xa.z); ta[3]=f2b(xa.w);
    ta[4]=f2b(xb_.x); ta[5]=f2b(xb_.y); ta[6]=f2b(xb_.z); ta[7]=f2b(xb_.w);
    tb[0]=f2b(xc.x); tb[1]=f2b(xc.y); tb[2]=f2b(xc.z); tb[3]=f2b(xc.w);
    tb[4]=f2b(xd.x); tb[5]=f2b(xd.y); tb[6]=f2b(xd.z); tb[7]=f2b(xd.w);
    bf16x8 af0 = *(const bf16x8*)ta;
    bf16x8 af1 = *(const bf16x8*)tb;

    for (int cc = 0; cc < 6; ++cc) {
        int ct = yg * 6 + cc;
        int which = ct / 12;
        int col0 = (ct % 12) * 64;
        const ushort* __restrict__ Wz = Wt + (size_t)which * HD * DIM;  // (768x64)
        ushort* __restrict__ Y = (which == 0) ? Q : (which == 1) ? K : V;
        float sc = (which == 0) ? SCALE2 : 1.f;
        #pragma unroll
        for (int nt = 0; nt < 4; ++nt) {
            int n = col0 + nt * 16 + ln;
            bf16x8 bf0 = *(const bf16x8*)&Wz[(size_t)n * DIM + q * 8];
            bf16x8 bf1 = *(const bf16x8*)&Wz[(size_t)n * DIM + 32 + q * 8];
            f32x4 acc = (f32x4){0.f, 0.f, 0.f, 0.f};
            acc = __builtin_amdgcn_mfma_f32_16x16x32_bf16(af0, bf0, acc, 0, 0, 0);
            acc = __builtin_amdgcn_mfma_f32_16x16x32_bf16(af1, bf1, acc, 0, 0, 0);
            #pragma unroll
            for (int r = 0; r < 4; ++r)
                Y[(size_t)(m0 + q * 4 + r) * HD + col0 + nt * 16 + ln] = f2b(acc[r] * sc);
        }
    }
}

// ---------------- Kernel 1b: Vt[s][d][t] = V[s][t][d] ----------------------
// XOR-swizzled transposed scalar writes (banks spread), vector reads un-swizzle.
__global__ __launch_bounds__(256) void vtrans_kernel(
    const ushort* __restrict__ V, ushort* __restrict__ Vt)
{
    __shared__ ushort tileT[64 * LDT];
    int tt = blockIdx.x, s = blockIdx.y;
    const ushort* __restrict__ Vp = V + (size_t)s * SLICE;
    ushort* __restrict__ Vo = Vt + (size_t)s * SLICE;
    int t = threadIdx.x;
    int r = t >> 3, c = (t & 7) * 8;
    ushort va[8] __attribute__((aligned(16)));
    ushort vb[8] __attribute__((aligned(16)));
    *(float4*)va = *(const float4*)&Vp[(size_t)(tt * 64 + r) * DIM + c];
    *(float4*)vb = *(const float4*)&Vp[(size_t)(tt * 64 + r + 32) * DIM + c];
    int g0 = ((r >> 3) ^ (c >> 3)) * 8 + (r & 7);
    int g1 = (((r + 32) >> 3) ^ (c >> 3)) * 8 + (r & 7);
    #pragma unroll
    for (int k = 0; k < 8; ++k) {
        tileT[(c + k) * LDT + g0] = va[k];
        tileT[(c + k) * LDT + g1] = vb[k];
    }
    __syncthreads();
    #pragma unroll
    for (int j = 0; j < 2; ++j) {
        int flat = t + 256 * j;
        int d = flat >> 3, tg = flat & 7;
        int sg = tg ^ ((d >> 3) & 7);
        float4 vv = *(const float4*)&tileT[d * LDT + sg * 8];
        *(float4*)&Vo[(size_t)d * TSEQ + tt * 64 + tg * 8] = vv;
    }
}

// ---------------- Kernel 2: MFMA flash attention (reg-prefetch dbuf) -------
// VERIFIED round-7 core, unchanged. grid (16 i-tiles, 48 slices), 256 thr =
// 4 waves; wave owns 32 i-rows. Next tile's Q/V loads issue right after the
// LDS-ready barrier into VGPRs; only 4 ds_write_b128 between barriers.
__global__ __launch_bounds__(256) void attn_kernel(
    const ushort* __restrict__ Qs, const ushort* __restrict__ Ks,
    const ushort* __restrict__ Vts, ushort* __restrict__ Zs)
{
    __shared__ ushort Qt[64 * LDQ];
    __shared__ ushort Vtile[64 * LDQ];
    __shared__ ushort Pw[128 * LDP];
    int itile = blockIdx.x, s = blockIdx.y;
    const ushort* __restrict__ Qp = Qs + (size_t)s * SLICE;
    const ushort* __restrict__ Kp = Ks + (size_t)s * SLICE;
    const ushort* __restrict__ Vp = Vts + (size_t)s * SLICE;   // [64][2048]
    ushort* __restrict__ Zp = Zs + (size_t)s * SLICE;
    int t = threadIdx.x, w = t >> 6, lane = t & 63;
    int ln = lane & 15, q = lane >> 4;

    bf16x8 kf[2][2];
    #pragma unroll
    for (int ih = 0; ih < 2; ++ih) {
        int i0 = itile * 128 + w * 32 + ih * 16 + ln;
        kf[ih][0] = *(const bf16x8*)&Kp[(size_t)i0 * DIM + q * 8];
        kf[ih][1] = *(const bf16x8*)&Kp[(size_t)i0 * DIM + 32 + q * 8];
    }
    f32x4 Of[2][4];
    #pragma unroll
    for (int ih = 0; ih < 2; ++ih)
        #pragma unroll
        for (int dt = 0; dt < 4; ++dt) Of[ih][dt] = (f32x4){0.f, 0.f, 0.f, 0.f};
    float lsum[2] = {0.f, 0.f};
    ushort* Pme = &Pw[w * 32 * LDP];

    int sr = t >> 3, sc = (t & 7) * 8;
    // prefetch tile 0
    float4 qa0 = *(const float4*)&Qp[(size_t)sr * DIM + sc];
    float4 qa1 = *(const float4*)&Qp[(size_t)(sr + 32) * DIM + sc];
    float4 va0 = *(const float4*)&Vp[(size_t)sr * TSEQ + sc];
    float4 va1 = *(const float4*)&Vp[(size_t)(sr + 32) * TSEQ + sc];

    for (int jt = 0; jt < TSEQ; jt += 64) {
        __syncthreads();                       // consumers of prev tile done
        *(float4*)&Qt[sr * LDQ + sc] = qa0;
        *(float4*)&Qt[(sr + 32) * LDQ + sc] = qa1;
        *(float4*)&Vtile[sr * LDQ + sc] = va0;
        *(float4*)&Vtile[(sr + 32) * LDQ + sc] = va1;
        __syncthreads();                       // tile ready
        if (jt + 64 < TSEQ) {                  // prefetch next tile into regs
            qa0 = *(const float4*)&Qp[(size_t)(jt + 64 + sr) * DIM + sc];
            qa1 = *(const float4*)&Qp[(size_t)(jt + 64 + sr + 32) * DIM + sc];
            va0 = *(const float4*)&Vp[(size_t)sr * TSEQ + jt + 64 + sc];
            va1 = *(const float4*)&Vp[(size_t)(sr + 32) * TSEQ + jt + 64 + sc];
        }

        // S^T = Q*K^T (Q pre-scaled: S is already in log2-units)
        f32x4 Sf[2][4];
        #pragma unroll
        for (int mt = 0; mt < 4; ++mt) {
            bf16x8 a0 = *(const bf16x8*)&Qt[(mt * 16 + ln) * LDQ + q * 8];
            bf16x8 a1 = *(const bf16x8*)&Qt[(mt * 16 + ln) * LDQ + 32 + q * 8];
            #pragma unroll
            for (int ih = 0; ih < 2; ++ih) {
                f32x4 acc = (f32x4){0.f, 0.f, 0.f, 0.f};
                acc = __builtin_amdgcn_mfma_f32_16x16x32_bf16(a0, kf[ih][0], acc, 0, 0, 0);
                acc = __builtin_amdgcn_mfma_f32_16x16x32_bf16(a1, kf[ih][1], acc, 0, 0, 0);
                Sf[ih][mt] = acc;
            }
        }
        // p = exp2(S); truncation-pack into wave-private LDS; l from truncated
        #pragma unroll
        for (int ih = 0; ih < 2; ++ih) {
            float ls = 0.f;
            #pragma unroll
            for (int mt = 0; mt < 4; ++mt) {
                float p0 = __builtin_amdgcn_exp2f(Sf[ih][mt][0]);
                float p1 = __builtin_amdgcn_exp2f(Sf[ih][mt][1]);
                float p2 = __builtin_amdgcn_exp2f(Sf[ih][mt][2]);
                float p3 = __builtin_amdgcn_exp2f(Sf[ih][mt][3]);
                unsigned int b0 = __float_as_uint(p0), b1 = __float_as_uint(p1);
                unsigned int b2 = __float_as_uint(p2), b3 = __float_as_uint(p3);
                unsigned int t1 = b1 & 0xFFFF0000u, t3 = b3 & 0xFFFF0000u;
                unsigned int h01 = (b0 >> 16) | t1;
                unsigned int h23 = (b2 >> 16) | t3;
                ls += __uint_as_float(h01 << 16) + __uint_as_float(t1)
                    + __uint_as_float(h23 << 16) + __uint_as_float(t3);
                *(uint2*)&Pme[(ih * 16 + ln) * LDP + mt * 16 + q * 4] =
                    make_uint2(h01, h23);
            }
            lsum[ih] += ls;
        }
        // Z += P * V^T (wave-private P: no barrier)
        bf16x8 pa[2][2];
        #pragma unroll
        for (int ih = 0; ih < 2; ++ih) {
            pa[ih][0] = *(const bf16x8*)&Pme[(ih * 16 + ln) * LDP + q * 8];
            pa[ih][1] = *(const bf16x8*)&Pme[(ih * 16 + ln) * LDP + 32 + q * 8];
        }
        #pragma unroll
        for (int dt = 0; dt < 4; ++dt) {
            bf16x8 vb0 = *(const bf16x8*)&Vtile[(dt * 16 + ln) * LDQ + q * 8];
            bf16x8 vb1 = *(const bf16x8*)&Vtile[(dt * 16 + ln) * LDQ + 32 + q * 8];
            #pragma unroll
            for (int ih = 0; ih < 2; ++ih) {
                Of[ih][dt] = __builtin_amdgcn_mfma_f32_16x16x32_bf16(pa[ih][0], vb0, Of[ih][dt], 0, 0, 0);
                Of[ih][dt] = __builtin_amdgcn_mfma_f32_16x16x32_bf16(pa[ih][1], vb1, Of[ih][dt], 0, 0, 0);
            }
        }
    }
    // final l reduction, normalize, store via LDS for coalesced writes
    float linv_r[2][4];
    #pragma unroll
    for (int ih = 0; ih < 2; ++ih) {
        float l = lsum[ih];
        l += __shfl_xor(l, 16);
        l += __shfl_xor(l, 32);
        float linv = 1.f / l;
        #pragma unroll
        for (int r = 0; r < 4; ++r) linv_r[ih][r] = __shfl(linv, q * 4 + r);
    }
    #pragma unroll
    for (int ih = 0; ih < 2; ++ih)
        #pragma unroll
        for (int dt = 0; dt < 4; ++dt)
            #pragma unroll
            for (int r = 0; r < 4; ++r)
                Pme[(ih * 16 + q * 4 + r) * LDP + dt * 16 + ln] =
                    f2b(Of[ih][dt][r] * linv_r[ih][r]);
    __syncthreads();
    int zr = t >> 1, zc = (t & 1) * 32;
    size_t zoff = (size_t)(itile * 128 + zr) * DIM + zc;
    #pragma unroll
    for (int c4 = 0; c4 < 4; ++c4)
        *(float4*)&Zp[zoff + c4 * 8] = *(const float4*)&Pw[zr * LDP + zc + c4 * 8];
}

// ---------------- Kernel 3: out = Z @ Wo (MFMA, fp32 out) ------------------
// M=8192, N=64, K=768. 256 one-wave blocks; 2 m-tiles per wave for ILP.
// (round-7 verbatim)
__global__ __launch_bounds__(64) void out_kernel(
    const ushort* __restrict__ Z, const ushort* __restrict__ Wot,
    float* __restrict__ out)
{
    int m0 = blockIdx.x * 32;
    int lane = threadIdx.x;
    int ln = lane & 15, q = lane >> 4;
    f32x4 acc[2][4];
    #pragma unroll
    for (int u = 0; u < 2; ++u)
        #pragma unroll
        for (int nt = 0; nt < 4; ++nt) acc[u][nt] = (f32x4){0.f, 0.f, 0.f, 0.f};
    for (int kc = 0; kc < 24; ++kc) {
        bf16x8 a0 = *(const bf16x8*)&Z[(size_t)(m0 + ln) * HD + kc * 32 + q * 8];
        bf16x8 a1 = *(const bf16x8*)&Z[(size_t)(m0 + 16 + ln) * HD + kc * 32 + q * 8];
        #pragma unroll
        for (int nt = 0; nt < 4; ++nt) {
            bf16x8 bf = *(const bf16x8*)&Wot[(size_t)(nt * 16 + ln) * HD + kc * 32 + q * 8];
            acc[0][nt] = __builtin_amdgcn_mfma_f32_16x16x32_bf16(a0, bf, acc[0][nt], 0, 0, 0);
            acc[1][nt] = __builtin_amdgcn_mfma_f32_16x16x32_bf16(a1, bf, acc[1][nt], 0, 0, 0);
        }
    }
    #pragma unroll
    for (int u = 0; u < 2; ++u)
        #pragma unroll
        for (int nt = 0; nt < 4; ++nt)
            #pragma unroll
            for (int r = 0; r < 4; ++r)
                out[(size_t)(m0 + u * 16 + q * 4 + r) * DIM + nt * 16 + ln] = acc[u][nt][r];
}

extern "C" void kernel_launch(void* const* d_in, const int* in_sizes, int n_in,
                              void* d_out, int out_size, void* d_ws, size_t ws_size,
                              hipStream_t stream)
{
    const float* x  = (const float*)d_in[0];
    const float* Wq = (const float*)d_in[1];
    const float* Wk = (const float*)d_in[2];
    const float* Wv = (const float*)d_in[3];
    const float* Wo = (const float*)d_in[4];
    float* out = (float*)d_out;

    const size_t n = (size_t)BT * HD;            // 6,291,456
    ushort* Q   = (ushort*)d_ws;
    ushort* K   = Q + n;
    ushort* V   = K + n;                         // Z aliases V (V dead after vtrans)
    ushort* Vt  = V + n;
    ushort* Wt  = Vt;                            // Wt lives only until qkv done;
    ushort* Wot = Vt + n;                        //   then vtrans overwrites with Vt
    ushort* Z   = V;

    prep_w<<<48, 256, 0, stream>>>(Wq, Wk, Wv, Wo, Wt, Wot);
    qkv_kernel<<<dim3(128, 6), 256, 0, stream>>>(x, Wt, Q, K, V);
    vtrans_kernel<<<dim3(32, 48), 256, 0, stream>>>(V, Vt);
    attn_kernel<<<dim3(16, 48), 256, 0, stream>>>(Q, K, Vt, Z);
    out_kernel<<<256, 64, 0, stream>>>(Z, Wot, out);
}

// Round 6
// 173.522 us; speedup vs baseline: 1.0461x; 1.0461x over previous
//
#include <hip/hip_runtime.h>
#include <hip/hip_bf16.h>

// MultiHeadAttention: B=4, T=2048, DIM=64, H=12. fp32 I/O.
// Flat-reshape semantics: QKV are (8192,768) row-major; attention slices are
// contiguous 131072-elem chunks. Roles: queries = K rows (i), keys = Q rows
// (j), values = V rows, softmax over j.
// Round 13: bisect (r12) proved the r8/r9/r10 corruption was the 4-wave
// out_kernel, NOT the 32x32 attn core. This round: round-9 32x32 attn core
// (in-register P, pair-by-construction PV, single barrier/iter dbuf) +
// round-7 out_kernel verbatim + qkv gridDim.y=6. out4 stays banned.

#define DIM 64
#define NH 12
#define HD 768
#define BT 8192
#define TSEQ 2048
#define NSLICE 48
#define SLICE (TSEQ*DIM)

#define LDQ 72   // LDS row stride (ushorts): 16B-aligned rows
#define LDT 72
#define LDP 72

typedef unsigned short ushort;
typedef __attribute__((ext_vector_type(8))) short bf16x8;
typedef __attribute__((ext_vector_type(4))) short bf16x4;
typedef __attribute__((ext_vector_type(4))) float f32x4;
typedef __attribute__((ext_vector_type(16))) float f32x16;
typedef __attribute__((ext_vector_type(4))) unsigned int uint32x4;

#define SCALE2 0.18033688011112042f   // 0.125 * log2(e)

__device__ __forceinline__ ushort f2b(float f) {
    union { float f; unsigned int i; } v; v.f = f;
    unsigned int x = v.i;
    return (ushort)((x + 0x7fffu + ((x >> 16) & 1u)) >> 16);  // RNE
}

// ---------------- prep: transpose + convert weights ------------------------
// 48 blocks: z = bx/12 (Wq,Wk,Wv,Wo), tile = bx%12.
__global__ __launch_bounds__(256) void prep_w(
    const float* __restrict__ Wq, const float* __restrict__ Wk,
    const float* __restrict__ Wv, const float* __restrict__ Wo,
    ushort* __restrict__ Wt, ushort* __restrict__ Wot)
{
    __shared__ float tile[64][65];
    int bx = blockIdx.x;
    int z = bx / 12, bt = bx % 12;
    const float* __restrict__ IN = (z == 0) ? Wq : (z == 1) ? Wk : (z == 2) ? Wv : Wo;
    int inStride  = (z < 3) ? HD : DIM;
    int outStride = (z < 3) ? DIM : HD;
    int rbase = (z < 3) ? 0 : bt * 64;
    int cbase = (z < 3) ? bt * 64 : 0;
    ushort* __restrict__ OUT = (z < 3) ? (Wt + (size_t)z * HD * DIM) : Wot;
    int t = threadIdx.x;
    int r = t >> 2, c0 = (t & 3) * 16;
    #pragma unroll
    for (int cc = 0; cc < 16; cc += 4) {
        float4 a = *(const float4*)&IN[(size_t)(rbase + r) * inStride + cbase + c0 + cc];
        tile[r][c0 + cc] = a.x; tile[r][c0 + cc + 1] = a.y;
        tile[r][c0 + cc + 2] = a.z; tile[r][c0 + cc + 3] = a.w;
    }
    __syncthreads();
    int cl = t >> 2, r0 = (t & 3) * 16;
    ushort tmp[16] __attribute__((aligned(16)));
    #pragma unroll
    for (int rr = 0; rr < 16; ++rr) tmp[rr] = f2b(tile[r0 + rr][cl]);
    *(float4*)&OUT[(size_t)(cbase + cl) * outStride + rbase + r0] = *(const float4*)tmp;
    *(float4*)&OUT[(size_t)(cbase + cl) * outStride + rbase + r0 + 8] = *(const float4*)&tmp[8];
}

// ---------------- Kernel 1: Q/K/V = x @ W (MFMA; x read as fp32) -----------
// grid (128 row-tiles, 6 col-groups), 256 thr = 4 waves; wave owns 16 rows
// and loops 6 col-tiles (3072 waves = 3/SIMD). Q written pre-scaled by SCALE2.
__global__ __launch_bounds__(256) void qkv_kernel(
    const float* __restrict__ x, const ushort* __restrict__ Wt,
    ushort* __restrict__ Q, ushort* __restrict__ K, ushort* __restrict__ V)
{
    int rt = blockIdx.x, yg = blockIdx.y;
    int t = threadIdx.x, w = t >> 6, lane = t & 63;
    int ln = lane & 15, q = lane >> 4;
    int m0 = rt * 64 + w * 16;

    // A-frags from fp32 x, converted in-reg (once per wave)
    float4 xa = *(const float4*)&x[(size_t)(m0 + ln) * DIM + q * 8];
    float4 xb_ = *(const float4*)&x[(size_t)(m0 + ln) * DIM + q * 8 + 4];
    float4 xc = *(const float4*)&x[(size_t)(m0 + ln) * DIM + 32 + q * 8];
    float4 xd = *(const float4*)&x[(size_t)(m0 + ln) * DIM + 32 + q * 8 + 4];
    ushort ta[8] __attribute__((aligned(16)));
    ushort tb[8] __attribute__((aligned(16)));
    ta[0]=f2b(xa.x); ta[1]=f2b(xa.y); ta[2]=f2b(xa.z); ta[3]=f2b(xa.w);
    ta[4]=f2b(xb_.x); ta[5]=f2b(xb_.y); ta[6]=f2b(xb_.z); ta[7]=f2b(xb_.w);
    tb[0]=f2b(xc.x); tb[1]=f2b(xc.y); tb[2]=f2b(xc.z); tb[3]=f2b(xc.w);
    tb[4]=f2b(xd.x); tb[5]=f2b(xd.y); tb[6]=f2b(xd.z); tb[7]=f2b(xd.w);
    bf16x8 af0 = *(const bf16x8*)ta;
    bf16x8 af1 = *(const bf16x8*)tb;

    for (int cc = 0; cc < 6; ++cc) {
        int ct = yg * 6 + cc;
        int which = ct / 12;
        int col0 = (ct % 12) * 64;
        const ushort* __restrict__ Wz = Wt + (size_t)which * HD * DIM;  // (768x64)
        ushort* __restrict__ Y = (which == 0) ? Q : (which == 1) ? K : V;
        float sc = (which == 0) ? SCALE2 : 1.f;
        #pragma unroll
        for (int nt = 0; nt < 4; ++nt) {
            int n = col0 + nt * 16 + ln;
            bf16x8 bf0 = *(const bf16x8*)&Wz[(size_t)n * DIM + q * 8];
            bf16x8 bf1 = *(const bf16x8*)&Wz[(size_t)n * DIM + 32 + q * 8];
            f32x4 acc = (f32x4){0.f, 0.f, 0.f, 0.f};
            acc = __builtin_amdgcn_mfma_f32_16x16x32_bf16(af0, bf0, acc, 0, 0, 0);
            acc = __builtin_amdgcn_mfma_f32_16x16x32_bf16(af1, bf1, acc, 0, 0, 0);
            #pragma unroll
            for (int r = 0; r < 4; ++r)
                Y[(size_t)(m0 + q * 4 + r) * HD + col0 + nt * 16 + ln] = f2b(acc[r] * sc);
        }
    }
}

// ---------------- Kernel 1b: Vt[s][d][t] = V[s][t][d] ----------------------
// XOR-swizzled transposed scalar writes (banks spread), vector reads un-swizzle.
__global__ __launch_bounds__(256) void vtrans_kernel(
    const ushort* __restrict__ V, ushort* __restrict__ Vt)
{
    __shared__ ushort tileT[64 * LDT];
    int tt = blockIdx.x, s = blockIdx.y;
    const ushort* __restrict__ Vp = V + (size_t)s * SLICE;
    ushort* __restrict__ Vo = Vt + (size_t)s * SLICE;
    int t = threadIdx.x;
    int r = t >> 3, c = (t & 7) * 8;
    ushort va[8] __attribute__((aligned(16)));
    ushort vb[8] __attribute__((aligned(16)));
    *(float4*)va = *(const float4*)&Vp[(size_t)(tt * 64 + r) * DIM + c];
    *(float4*)vb = *(const float4*)&Vp[(size_t)(tt * 64 + r + 32) * DIM + c];
    int g0 = ((r >> 3) ^ (c >> 3)) * 8 + (r & 7);
    int g1 = (((r + 32) >> 3) ^ (c >> 3)) * 8 + (r & 7);
    #pragma unroll
    for (int k = 0; k < 8; ++k) {
        tileT[(c + k) * LDT + g0] = va[k];
        tileT[(c + k) * LDT + g1] = vb[k];
    }
    __syncthreads();
    #pragma unroll
    for (int j = 0; j < 2; ++j) {
        int flat = t + 256 * j;
        int d = flat >> 3, tg = flat & 7;
        int sg = tg ^ ((d >> 3) & 7);
        float4 vv = *(const float4*)&tileT[d * LDT + sg * 8];
        *(float4*)&Vo[(size_t)d * TSEQ + tt * 64 + tg * 8] = vv;
    }
}

// ---------------- Kernel 2: MFMA flash attention (32x32, reg-P, dbuf) ------
// grid (16 i-tiles, 48 slices), 256 thr = 4 waves; wave owns 32 i-rows.
// S^T via mfma_32x32x16 (A=Q rows j, B=K rows i): lane (hi,i5) holds, for its
// own i=i5 column, acc reg r = row j=(r&3)+8*(r>>2)+4hi [m74/m101-verified
// D-map]. exp2+truncation-pack gives PA words in reg order; the PV B-operand
// loads V^T rows in the SAME j pattern (two ds_read_b64: rows 4hi+{0..3} and
// 4hi+{8..11}), so A/B elements pair j-for-j for ANY internal k-map
// (pair-by-construction). No P LDS traffic; single barrier per j-tile.
__global__ __launch_bounds__(256, 3) void attn_kernel(
    const ushort* __restrict__ Qs, const ushort* __restrict__ Ks,
    const ushort* __restrict__ Vts, ushort* __restrict__ Zs)
{
    __shared__ ushort sh[4 * 64 * LDQ];   // [Qt0][Qt1][Vt0][Vt1]; epilogue reuses
    int itile = blockIdx.x, s = blockIdx.y;
    const ushort* __restrict__ Qp = Qs + (size_t)s * SLICE;
    const ushort* __restrict__ Kp = Ks + (size_t)s * SLICE;
    const ushort* __restrict__ Vp = Vts + (size_t)s * SLICE;   // [64][2048]
    ushort* __restrict__ Zp = Zs + (size_t)s * SLICE;
    int t = threadIdx.x, w = t >> 6, lane = t & 63;
    int i5 = lane & 31, hi = lane >> 5;

    // K fragments (B-operand): lane holds K[i0+i5][c*16 + hi*8 + e]
    bf16x8 kf[4];
    {
        size_t krow = (size_t)(itile * 128 + w * 32 + i5) * DIM;
        #pragma unroll
        for (int c = 0; c < 4; ++c)
            kf[c] = *(const bf16x8*)&Kp[krow + c * 16 + hi * 8];
    }

    f32x16 Of0, Of1;
    #pragma unroll
    for (int r = 0; r < 16; ++r) { Of0[r] = 0.f; Of1[r] = 0.f; }
    float lsum = 0.f;

    int sr = t >> 3, sc = (t & 7) * 8;
    const ushort* qsrc0 = &Qp[(size_t)sr * DIM + sc];
    const ushort* qsrc1 = &Qp[(size_t)(sr + 32) * DIM + sc];
    const ushort* vsrc0 = &Vp[(size_t)sr * TSEQ + sc];
    const ushort* vsrc1 = &Vp[(size_t)(sr + 32) * TSEQ + sc];

    // prologue: tile 0 -> buf 0, prefetch tile 1 into regs
    float4 qa0 = *(const float4*)qsrc0;
    float4 qa1 = *(const float4*)qsrc1;
    float4 va0 = *(const float4*)vsrc0;
    float4 va1 = *(const float4*)vsrc1;
    *(float4*)&sh[sr * LDQ + sc] = qa0;
    *(float4*)&sh[(sr + 32) * LDQ + sc] = qa1;
    *(float4*)&sh[2 * 64 * LDQ + sr * LDQ + sc] = va0;
    *(float4*)&sh[2 * 64 * LDQ + (sr + 32) * LDQ + sc] = va1;
    qa0 = *(const float4*)(qsrc0 + 64 * DIM);
    qa1 = *(const float4*)(qsrc1 + 64 * DIM);
    va0 = *(const float4*)(vsrc0 + 64);
    va1 = *(const float4*)(vsrc1 + 64);
    __syncthreads();

    for (int tt = 0; tt < 32; ++tt) {
        int ib = tt & 1;
        const ushort* Qc = sh + ib * (64 * LDQ);
        const ushort* Vc = sh + (2 + ib) * (64 * LDQ);
        // stage next tile into the other buffer; issue loads for tile tt+2
        if (tt < 31) {
            ushort* Qn = sh + (ib ^ 1) * (64 * LDQ);
            ushort* Vn = sh + (2 + (ib ^ 1)) * (64 * LDQ);
            *(float4*)&Qn[sr * LDQ + sc] = qa0;
            *(float4*)&Qn[(sr + 32) * LDQ + sc] = qa1;
            *(float4*)&Vn[sr * LDQ + sc] = va0;
            *(float4*)&Vn[(sr + 32) * LDQ + sc] = va1;
            if (tt < 30) {
                size_t qo = (size_t)(tt + 2) * 64 * DIM;
                int vo = (tt + 2) * 64;
                qa0 = *(const float4*)(qsrc0 + qo);
                qa1 = *(const float4*)(qsrc1 + qo);
                va0 = *(const float4*)(vsrc0 + vo);
                va1 = *(const float4*)(vsrc1 + vo);
            }
        }
        #pragma unroll
        for (int js = 0; js < 2; ++js) {
            // S^T (32j x 32i), Q pre-scaled: S already in log2-units
            f32x16 acc;
            #pragma unroll
            for (int r = 0; r < 16; ++r) acc[r] = 0.f;
            #pragma unroll
            for (int c = 0; c < 4; ++c) {
                bf16x8 aQ = *(const bf16x8*)&Qc[(js * 32 + i5) * LDQ + c * 16 + hi * 8];
                acc = __builtin_amdgcn_mfma_f32_32x32x16_bf16(aQ, kf[c], acc, 0, 0, 0);
            }
            // p = exp2(S); truncation-pack pairs (low short = even reg);
            // l summed from the truncated values (matches P exactly)
            unsigned wv[8];
            float ls = 0.f;
            #pragma unroll
            for (int k = 0; k < 8; ++k) {
                float p0 = __builtin_amdgcn_exp2f(acc[2 * k]);
                float p1 = __builtin_amdgcn_exp2f(acc[2 * k + 1]);
                unsigned int b0 = __float_as_uint(p0), b1 = __float_as_uint(p1);
                unsigned int t1 = b1 & 0xFFFF0000u;
                unsigned int h = (b0 >> 16) | t1;
                ls += __uint_as_float(h << 16) + __uint_as_float(t1);
                wv[k] = h;
            }
            lsum += ls;
            uint32x4 u0 = { wv[0], wv[1], wv[2], wv[3] };  // regs 0..7  -> j=(e&3)+8*(e>>2)+4hi
            uint32x4 u1 = { wv[4], wv[5], wv[6], wv[7] };  // regs 8..15 -> j=16+(e&3)+8*(e>>2)+4hi
            bf16x8 pa0 = __builtin_bit_cast(bf16x8, u0);
            bf16x8 pa1 = __builtin_bit_cast(bf16x8, u1);
            // Z += P * V: B slot (hi,e) loads V^T row j matching pa's reg order
            #pragma unroll
            for (int dt = 0; dt < 2; ++dt) {
                int vbase = (dt * 32 + i5) * LDQ + js * 32 + 4 * hi;
                bf16x4 v0a = *(const bf16x4*)&Vc[vbase];
                bf16x4 v0b = *(const bf16x4*)&Vc[vbase + 8];
                bf16x4 v1a = *(const bf16x4*)&Vc[vbase + 16];
                bf16x4 v1b = *(const bf16x4*)&Vc[vbase + 24];
                bf16x8 vb0 = __builtin_shufflevector(v0a, v0b, 0, 1, 2, 3, 4, 5, 6, 7);
                bf16x8 vb1 = __builtin_shufflevector(v1a, v1b, 0, 1, 2, 3, 4, 5, 6, 7);
                if (dt == 0) {
                    Of0 = __builtin_amdgcn_mfma_f32_32x32x16_bf16(pa0, vb0, Of0, 0, 0, 0);
                    Of0 = __builtin_amdgcn_mfma_f32_32x32x16_bf16(pa1, vb1, Of0, 0, 0, 0);
                } else {
                    Of1 = __builtin_amdgcn_mfma_f32_32x32x16_bf16(pa0, vb0, Of1, 0, 0, 0);
                    Of1 = __builtin_amdgcn_mfma_f32_32x32x16_bf16(pa1, vb1, Of1, 0, 0, 0);
                }
            }
        }
        __syncthreads();
    }

    // l: partner lane (hi^1) holds the complementary j's for the same i=i5
    float l = lsum + __shfl_xor(lsum, 32);
    float linv = 1.f / l;
    // normalize + stage 128x64 output tile into LDS for coalesced writes
    #pragma unroll
    for (int r = 0; r < 16; ++r) {
        int cr = (r & 3) + 8 * (r >> 2);
        float li = __shfl(linv, cr + 4 * hi);
        int row = w * 32 + cr + 4 * hi;
        sh[row * LDQ + i5]      = f2b(Of0[r] * li);
        sh[row * LDQ + 32 + i5] = f2b(Of1[r] * li);
    }
    __syncthreads();
    int zr = t >> 1, zc = (t & 1) * 32;
    size_t zoff = (size_t)(itile * 128 + zr) * DIM + zc;
    #pragma unroll
    for (int c4 = 0; c4 < 4; ++c4)
        *(float4*)&Zp[zoff + c4 * 8] = *(const float4*)&sh[zr * LDQ + zc + c4 * 8];
}

// ---------------- Kernel 3: out = Z @ Wo (MFMA, fp32 out) ------------------
// M=8192, N=64, K=768. 256 one-wave blocks; 2 m-tiles per wave for ILP.
// (round-7 verbatim; the 4-wave rewrite is banned pending diagnosis)
__global__ __launch_bounds__(64) void out_kernel(
    const ushort* __restrict__ Z, const ushort* __restrict__ Wot,
    float* __restrict__ out)
{
    int m0 = blockIdx.x * 32;
    int lane = threadIdx.x;
    int ln = lane & 15, q = lane >> 4;
    f32x4 acc[2][4];
    #pragma unroll
    for (int u = 0; u < 2; ++u)
        #pragma unroll
        for (int nt = 0; nt < 4; ++nt) acc[u][nt] = (f32x4){0.f, 0.f, 0.f, 0.f};
    for (int kc = 0; kc < 24; ++kc) {
        bf16x8 a0 = *(const bf16x8*)&Z[(size_t)(m0 + ln) * HD + kc * 32 + q * 8];
        bf16x8 a1 = *(const bf16x8*)&Z[(size_t)(m0 + 16 + ln) * HD + kc * 32 + q * 8];
        #pragma unroll
        for (int nt = 0; nt < 4; ++nt) {
            bf16x8 bf = *(const bf16x8*)&Wot[(size_t)(nt * 16 + ln) * HD + kc * 32 + q * 8];
            acc[0][nt] = __builtin_amdgcn_mfma_f32_16x16x32_bf16(a0, bf, acc[0][nt], 0, 0, 0);
            acc[1][nt] = __builtin_amdgcn_mfma_f32_16x16x32_bf16(a1, bf, acc[1][nt], 0, 0, 0);
        }
    }
    #pragma unroll
    for (int u = 0; u < 2; ++u)
        #pragma unroll
        for (int nt = 0; nt < 4; ++nt)
            #pragma unroll
            for (int r = 0; r < 4; ++r)
                out[(size_t)(m0 + u * 16 + q * 4 + r) * DIM + nt * 16 + ln] = acc[u][nt][r];
}

extern "C" void kernel_launch(void* const* d_in, const int* in_sizes, int n_in,
                              void* d_out, int out_size, void* d_ws, size_t ws_size,
                              hipStream_t stream)
{
    const float* x  = (const float*)d_in[0];
    const float* Wq = (const float*)d_in[1];
    const float* Wk = (const float*)d_in[2];
    const float* Wv = (const float*)d_in[3];
    const float* Wo = (const float*)d_in[4];
    float* out = (float*)d_out;

    const size_t n = (size_t)BT * HD;            // 6,291,456
    ushort* Q   = (ushort*)d_ws;
    ushort* K   = Q + n;
    ushort* V   = K + n;                         // Z aliases V (V dead after vtrans)
    ushort* Vt  = V + n;
    ushort* Wt  = Vt;                            // Wt lives only until qkv done;
    ushort* Wot = Vt + n;                        //   then vtrans overwrites with Vt
    ushort* Z   = V;

    prep_w<<<48, 256, 0, stream>>>(Wq, Wk, Wv, Wo, Wt, Wot);
    qkv_kernel<<<dim3(128, 6), 256, 0, stream>>>(x, Wt, Q, K, V);
    vtrans_kernel<<<dim3(32, 48), 256, 0, stream>>>(V, Vt);
    attn_kernel<<<dim3(16, 48), 256, 0, stream>>>(Q, K, Vt, Z);
    out_kernel<<<256, 64, 0, stream>>>(Z, Wot, out);
}